// Round 10
// baseline (207.738 us; speedup 1.0000x reference)
//
#include <hip/hip_runtime.h>

// ---------- types ----------
typedef __bf16 bf16x8 __attribute__((ext_vector_type(8)));
typedef float  f32x4  __attribute__((ext_vector_type(4)));
typedef unsigned short u16x8 __attribute__((ext_vector_type(8)));

#define IN_CH  256
#define OUT_CH 256
#define HIDDEN 2048
#define NB     8
#define NT     4000
#define NROW   32000   // NB*NT
#define F1LD   66      // f1t leading dim (odd word stride -> spread banks)

__device__ __forceinline__ unsigned short bfbits(float f) {
    __bf16 h = (__bf16)f;                       // native cvt (RTNE)
    return *reinterpret_cast<unsigned short*>(&h);
}
__device__ __forceinline__ float bf2f(unsigned short h) {
    return __uint_as_float(((unsigned)h) << 16);
}

#define GLOAD_LDS16(g, l) \
    __builtin_amdgcn_global_load_lds((const __attribute__((address_space(1))) void*)(g), \
                                     (__attribute__((address_space(3))) void*)(l), 16, 0, 0)

// ---------- 1. fp32 -> bf16 convert (weights) ----------
__global__ void cvt_kernel(const float* __restrict__ in,
                           unsigned short* __restrict__ out, int n4) {
    int i = blockIdx.x * blockDim.x + threadIdx.x;
    if (i >= n4) return;
    float4 v = reinterpret_cast<const float4*>(in)[i];
    ushort4 o;
    o.x = bfbits(v.x); o.y = bfbits(v.y); o.z = bfbits(v.z); o.w = bfbits(v.w);
    reinterpret_cast<ushort4*>(out)[i] = o;
}

// ---------- 2. partial mean/var reduction over T ----------
__global__ void reduce_kernel(const float* __restrict__ x,
                              float* __restrict__ psum, float* __restrict__ psq) {
    int c = threadIdx.x;
    int blk = blockIdx.x;
    int b = blk >> 5, tc = blk & 31;
    const float* base = x + ((size_t)b * NT + tc * 125) * IN_CH + c;
    float s = 0.f, q = 0.f;
    for (int t = 0; t < 125; ++t) {
        float v = base[(size_t)t * IN_CH];
        s += v; q += v * v;
    }
    psum[blk * IN_CH + c] = s;
    psq [blk * IN_CH + c] = q;
}

// ---------- 3. gate: mean/std -> logits -> probs -> losses ----------
__global__ __launch_bounds__(256) void gate_kernel(
    const float* __restrict__ psum, const float* __restrict__ psq,
    const float* __restrict__ gate_w, const float* __restrict__ gate_b,
    const float* __restrict__ tau, float* __restrict__ probs,
    float* __restrict__ losses) {
    __shared__ float gi[NB][2 * IN_CH];
    __shared__ float lgt[16];
    int tid = threadIdx.x;
    for (int b = 0; b < NB; ++b) {
        float s = 0.f, q = 0.f;
        for (int p = 0; p < 32; ++p) {
            s += psum[(b * 32 + p) * IN_CH + tid];
            q += psq [(b * 32 + p) * IN_CH + tid];
        }
        float mean = s * (1.f / 4000.f);
        float var  = (q - s * s * (1.f / 4000.f)) * (1.f / 3999.f);  // ddof=1
        gi[b][tid]          = mean;
        gi[b][IN_CH + tid]  = sqrtf(fmaxf(var, 0.f));
    }
    __syncthreads();
    if (tid < 16) {
        int b = tid >> 1, k = tid & 1;
        float d = 0.f;
        for (int i = 0; i < 2 * IN_CH; ++i) d += gi[b][i] * gate_w[k * 2 * IN_CH + i];
        lgt[tid] = tau[0] * (d + gate_b[k]);
    }
    __syncthreads();
    if (tid == 0) {
        float pr[16];
        float i0 = 0.f, i1 = 0.f, sp = 0.f;
        for (int b = 0; b < NB; ++b) {
            float a = lgt[b * 2], c2 = lgt[b * 2 + 1];
            float mx = fmaxf(a, c2);
            float e0 = expf(a - mx), e1 = expf(c2 - mx);
            float inv = 1.f / (e0 + e1);
            float q0 = e0 * inv, q1 = e1 * inv;
            pr[b * 2] = q0; pr[b * 2 + 1] = q1;
            i0 += q0; i1 += q1;
            float nrm = sqrtf(q0 * q0 + q1 * q1) + 1e-8f;
            sp += (q0 + q1) / nrm;
        }
        losses[0] = 0.1f * sp * (1.f / 8.f);
        i0 *= (1.f / 8.f); i1 *= (1.f / 8.f);
        float meanI = 0.5f * (i0 + i1);
        float stdI  = fabsf(i0 - i1) * 0.7071067811865476f;
        float cv = stdI / (meanI + 1e-8f);
        losses[1] = 0.01f * cv * cv;
        for (int t = 0; t < 16; ++t) probs[t] = pr[t];
    }
}

// ---------- 4. fused GEMM1(relu)+GEMM2 -> mixed output, M=64, wave=32r x 128oc ----
// 500 blocks x 256 threads (4 waves = 2 rb x 2 ch). 128 VGPR + 80 AGPR = 208
// <= 256 -> 2 waves/SIMD (R9-verified: Occupancy 20%, no spill).
// Mixture fusion (zero extra registers): after chunk 3 (hidden 0..255 = small
// branch), acc2 *= (p0+p1)/p0; final store mix = p0*acc2
//   = p0*(full) + p1*(small)  -- conv then reads ONE bf16 array.
__global__ __launch_bounds__(256, 2) void gemm_kernel(
    const float* __restrict__ x,
    const unsigned short* __restrict__ w1b,   // [2048][256] bf16
    const unsigned short* __restrict__ w2b,   // [256][2048] bf16
    const float* __restrict__ b1,
    const float* __restrict__ probs,          // [8][2]
    unsigned short* __restrict__ mix) {       // [32000][256] bf16 (pre-mixed)
    __shared__ __align__(16) unsigned short w1c[64 * 256];   // 32 KB
    __shared__ __align__(16) unsigned short w2c[256 * 64];   // 32 KB
    __shared__ __align__(16) unsigned short f1t[64 * F1LD];  // 8.25 KB

    const int tid   = threadIdx.x;
    const int lane  = tid & 63;
    const int wv    = tid >> 6;       // 0..3
    const int rb    = wv & 1;         // 32-row band
    const int ch    = wv >> 1;        // 0..1 oc half (128 each)
    const int m0    = blockIdx.x * 64;
    const int l15   = lane & 15;
    const int lg    = lane >> 4;      // 0..3

    // ---- x fragments to registers: xr[rt][kk], rows m0 + rb*32 + rt*16 + l15 ----
    bf16x8 xr[2][8];
#pragma unroll
    for (int rt = 0; rt < 2; ++rt) {
        const float* xrow = x + (size_t)(m0 + rb * 32 + rt * 16 + l15) * IN_CH;
#pragma unroll
        for (int kk = 0; kk < 8; ++kk) {
            float4 v0 = *reinterpret_cast<const float4*>(xrow + kk * 32 + lg * 8);
            float4 v1 = *reinterpret_cast<const float4*>(xrow + kk * 32 + lg * 8 + 4);
            bf16x8 h;
            h[0] = (__bf16)v0.x; h[1] = (__bf16)v0.y; h[2] = (__bf16)v0.z; h[3] = (__bf16)v0.w;
            h[4] = (__bf16)v1.x; h[5] = (__bf16)v1.y; h[6] = (__bf16)v1.z; h[7] = (__bf16)v1.w;
            xr[rt][kk] = h;
        }
    }

    f32x4 acc2[2][8];
#pragma unroll
    for (int rt = 0; rt < 2; ++rt)
#pragma unroll
        for (int t = 0; t < 8; ++t) { acc2[rt][t][0]=0.f; acc2[rt][t][1]=0.f; acc2[rt][t][2]=0.f; acc2[rt][t][3]=0.f; }

#pragma unroll 1
    for (int chunk = 0; chunk < 32; ++chunk) {
        // ---- stage THIS chunk's weights into the single buffer ----
        {
            const int h0 = chunk * 64;
            const unsigned short* w1s = w1b + (size_t)h0 * IN_CH;
            const unsigned short* w2s = w2b + h0;
#pragma unroll
            for (int i = 0; i < 8; ++i) {
                int seg = i * 4 + wv;                       // 0..31
                int r1 = seg * 2 + (lane >> 5);
                int c1 = ((lane & 31) * 8) ^ ((r1 & 7) << 3);
                GLOAD_LDS16(w1s + r1 * 256 + c1, &w1c[seg * 512]);
                int r2 = seg * 8 + (lane >> 3);
                int c2 = ((lane & 7) * 8) ^ ((r2 & 7) << 3);
                GLOAD_LDS16(w2s + (size_t)r2 * HIDDEN + c2, &w2c[seg * 512]);
            }
        }

        __syncthreads();   // [A] vmcnt drained -> weights ready

        // ---- GEMM1: f1[64][64]; wave (rb,ch): rows rb*32+.., h ch*32+ht*16+l15 ----
        f32x4 acc1[2][2];
#pragma unroll
        for (int rt = 0; rt < 2; ++rt)
#pragma unroll
            for (int ht = 0; ht < 2; ++ht) { acc1[rt][ht][0]=0.f; acc1[rt][ht][1]=0.f; acc1[rt][ht][2]=0.f; acc1[rt][ht][3]=0.f; }
#pragma unroll
        for (int kk = 0; kk < 8; ++kk) {
            const int kE = kk * 32 + lg * 8;
            bf16x8 bb[2];
#pragma unroll
            for (int ht = 0; ht < 2; ++ht) {
                const int hl = ch * 32 + ht * 16 + l15;
                bb[ht] = *reinterpret_cast<const bf16x8*>(
                    &w1c[hl * 256 + (kE ^ ((hl & 7) << 3))]);
            }
#pragma unroll
            for (int rt = 0; rt < 2; ++rt)
#pragma unroll
                for (int ht = 0; ht < 2; ++ht)
                    acc1[rt][ht] = __builtin_amdgcn_mfma_f32_16x16x32_bf16(
                        xr[rt][kk], bb[ht], acc1[rt][ht], 0, 0, 0);
        }
        // bias + relu -> f1t
#pragma unroll
        for (int ht = 0; ht < 2; ++ht) {
            const int hl = ch * 32 + ht * 16 + l15;
            const float bias = b1[chunk * 64 + hl];   // L2-hit scalar
#pragma unroll
            for (int rt = 0; rt < 2; ++rt)
#pragma unroll
                for (int r = 0; r < 4; ++r) {
                    float v = fmaxf(acc1[rt][ht][r] + bias, 0.f);
                    int rr = rb * 32 + rt * 16 + lg * 4 + r;
                    f1t[rr * F1LD + hl] = bfbits(v);
                }
        }

        __syncthreads();   // [B] f1t ready

        // ---- GEMM2: acc2 += f1 @ w2_chunk^T; wave: 32r x 128oc ----
#pragma unroll
        for (int kk = 0; kk < 2; ++kk) {
            const int kE = kk * 32 + lg * 8;
            bf16x8 a2[2];
#pragma unroll
            for (int rt = 0; rt < 2; ++rt)
                a2[rt] = *reinterpret_cast<const bf16x8*>(
                    &f1t[(rb * 32 + rt * 16 + l15) * F1LD + kE]);
#pragma unroll
            for (int t = 0; t < 8; ++t) {
                int oc = ch * 128 + t * 16 + l15;
                bf16x8 b2 = *reinterpret_cast<const bf16x8*>(
                    &w2c[oc * 64 + (kE ^ ((oc & 7) << 3))]);
#pragma unroll
                for (int rt = 0; rt < 2; ++rt)
                    acc2[rt][t] = __builtin_amdgcn_mfma_f32_16x16x32_bf16(
                        a2[rt], b2, acc2[rt][t], 0, 0, 0);
            }
        }

        if (chunk == 3) {   // hidden 0..255 done: acc2 = small. Rescale so the
                            // final p0*acc2 equals p0*full + p1*small.
#pragma unroll
            for (int rt = 0; rt < 2; ++rt)
#pragma unroll
                for (int r = 0; r < 4; ++r) {
                    int rr = m0 + rb * 32 + rt * 16 + lg * 4 + r;
                    int bb = rr / 4000;
                    float p0 = probs[bb * 2], p1 = probs[bb * 2 + 1];
                    float ratio = (p0 + p1) / fmaxf(p0, 1e-30f);
#pragma unroll
                    for (int t = 0; t < 8; ++t)
                        acc2[rt][t][r] *= ratio;
                }
        }

        __syncthreads();   // [C] w1c/w2c/f1t reads done -> next stage may overwrite
    }
    // final: mix = p0 * acc2 (= p0*full + p1*small)
#pragma unroll
    for (int rt = 0; rt < 2; ++rt)
#pragma unroll
        for (int r = 0; r < 4; ++r) {
            int rr = m0 + rb * 32 + rt * 16 + lg * 4 + r;
            int bb = rr / 4000;
            float p0 = probs[bb * 2];
#pragma unroll
            for (int t = 0; t < 8; ++t) {
                int oc = ch * 128 + t * 16 + l15;
                mix[(size_t)rr * OUT_CH + oc] = bfbits(p0 * acc2[rt][t][r]);
            }
        }
}

// ---------- 5. depthwise conv (39 taps) + identity, direct from global ----------
// mix is L2/L3-resident (16.4MB) -> no LDS staging (guide: common-mistake #7).
// 2000 blocks x 256 threads; thread = channel c, 16 t-outputs in 2 g-groups of 8.
// R2-proven register structure (vwin[46], all-static indices -> no scratch).
__global__ __launch_bounds__(256) void conv_kernel(
    const unsigned short* __restrict__ mix,
    const float* __restrict__ conv_w,   // [256][1][39]
    float* __restrict__ out) {
    const int c   = threadIdx.x;
    const int blk = blockIdx.x;
    const int b   = blk / 250;
    const int t0  = (blk % 250) * 16;

    float cw[39];
#pragma unroll
    for (int j = 0; j < 39; ++j) cw[j] = conv_w[c * 39 + j];

    const unsigned short* mb = mix + (size_t)b * NT * OUT_CH + c;

#pragma unroll 1
    for (int g = 0; g < 2; ++g) {
        const int u0 = t0 + g * 8;
        float vwin[46];
#pragma unroll
        for (int i = 0; i < 46; ++i) {
            int t = u0 - 19 + i;
            vwin[i] = (t >= 0 && t < NT) ? bf2f(mb[(size_t)t * OUT_CH]) : 0.f;
        }
        float acc[8];
#pragma unroll
        for (int o = 0; o < 8; ++o) {
            float a = vwin[o + 19];          // identity (xp + conv)
#pragma unroll
            for (int j = 0; j < 39; ++j)
                a += cw[j] * vwin[o + j];
            acc[o] = a;
        }
#pragma unroll
        for (int o = 0; o < 8; ++o)
            out[((size_t)b * NT + u0 + o) * OUT_CH + c] = acc[o];
    }
}

// ---------- launch ----------
extern "C" void kernel_launch(void* const* d_in, const int* in_sizes, int n_in,
                              void* d_out, int out_size, void* d_ws, size_t ws_size,
                              hipStream_t stream) {
    const float* x      = (const float*)d_in[0];
    const float* w1     = (const float*)d_in[1];
    const float* b1     = (const float*)d_in[2];
    const float* w2     = (const float*)d_in[3];
    const float* conv_w = (const float*)d_in[4];
    const float* gate_w = (const float*)d_in[5];
    const float* gate_b = (const float*)d_in[6];
    const float* tau    = (const float*)d_in[7];
    float* out = (float*)d_out;

    char* ws = (char*)d_ws;
    unsigned short* w1b = (unsigned short*)(ws);
    unsigned short* w2b = (unsigned short*)(ws + 1048576);
    unsigned short* mix = (unsigned short*)(ws + 2097152);
    float* psum  = (float*)(ws + 2097152 + 2 * 16384000);
    float* psq   = psum + 256 * 256;
    float* probs = psq + 256 * 256;

    cvt_kernel<<<dim3(512), dim3(256), 0, stream>>>(w1, w1b, 131072);
    cvt_kernel<<<dim3(512), dim3(256), 0, stream>>>(w2, w2b, 131072);
    reduce_kernel<<<dim3(256), dim3(256), 0, stream>>>(x, psum, psq);
    gate_kernel<<<dim3(1), dim3(256), 0, stream>>>(psum, psq, gate_w, gate_b, tau,
                                                   probs, out + 8192000);
    gemm_kernel<<<dim3(500), dim3(256), 0, stream>>>(x, w1b, w2b, b1, probs, mix);
    conv_kernel<<<dim3(2000), dim3(256), 0, stream>>>(mix, conv_w, out);
}

// Round 11
// 167.627 us; speedup vs baseline: 1.2393x; 1.2393x over previous
//
#include <hip/hip_runtime.h>

// ---------- types ----------
typedef __bf16 bf16x8 __attribute__((ext_vector_type(8)));
typedef float  f32x4  __attribute__((ext_vector_type(4)));
typedef unsigned short u16x8 __attribute__((ext_vector_type(8)));

#define IN_CH  256
#define OUT_CH 256
#define HIDDEN 2048
#define NB     8
#define NT     4000
#define NROW   32000   // NB*NT
#define F1LD   66      // f1t leading dim (odd word stride -> spread banks)

__device__ __forceinline__ unsigned short bfbits(float f) {
    __bf16 h = (__bf16)f;                       // native cvt (RTNE)
    return *reinterpret_cast<unsigned short*>(&h);
}
__device__ __forceinline__ float bf2f(unsigned short h) {
    return __uint_as_float(((unsigned)h) << 16);
}

#define GLOAD_LDS16(g, l) \
    __builtin_amdgcn_global_load_lds((const __attribute__((address_space(1))) void*)(g), \
                                     (__attribute__((address_space(3))) void*)(l), 16, 0, 0)

// ---------- 1. fp32 -> bf16 convert (weights) ----------
__global__ void cvt_kernel(const float* __restrict__ in,
                           unsigned short* __restrict__ out, int n4) {
    int i = blockIdx.x * blockDim.x + threadIdx.x;
    if (i >= n4) return;
    float4 v = reinterpret_cast<const float4*>(in)[i];
    ushort4 o;
    o.x = bfbits(v.x); o.y = bfbits(v.y); o.z = bfbits(v.z); o.w = bfbits(v.w);
    reinterpret_cast<ushort4*>(out)[i] = o;
}

// ---------- 2. partial mean/var reduction over T ----------
__global__ void reduce_kernel(const float* __restrict__ x,
                              float* __restrict__ psum, float* __restrict__ psq) {
    int c = threadIdx.x;
    int blk = blockIdx.x;
    int b = blk >> 5, tc = blk & 31;
    const float* base = x + ((size_t)b * NT + tc * 125) * IN_CH + c;
    float s = 0.f, q = 0.f;
    for (int t = 0; t < 125; ++t) {
        float v = base[(size_t)t * IN_CH];
        s += v; q += v * v;
    }
    psum[blk * IN_CH + c] = s;
    psq [blk * IN_CH + c] = q;
}

// ---------- 3. gate: mean/std -> logits -> probs -> losses ----------
__global__ __launch_bounds__(256) void gate_kernel(
    const float* __restrict__ psum, const float* __restrict__ psq,
    const float* __restrict__ gate_w, const float* __restrict__ gate_b,
    const float* __restrict__ tau, float* __restrict__ probs,
    float* __restrict__ losses) {
    __shared__ float gi[NB][2 * IN_CH];
    __shared__ float lgt[16];
    int tid = threadIdx.x;
    for (int b = 0; b < NB; ++b) {
        float s = 0.f, q = 0.f;
        for (int p = 0; p < 32; ++p) {
            s += psum[(b * 32 + p) * IN_CH + tid];
            q += psq [(b * 32 + p) * IN_CH + tid];
        }
        float mean = s * (1.f / 4000.f);
        float var  = (q - s * s * (1.f / 4000.f)) * (1.f / 3999.f);  // ddof=1
        gi[b][tid]          = mean;
        gi[b][IN_CH + tid]  = sqrtf(fmaxf(var, 0.f));
    }
    __syncthreads();
    if (tid < 16) {
        int b = tid >> 1, k = tid & 1;
        float d = 0.f;
        for (int i = 0; i < 2 * IN_CH; ++i) d += gi[b][i] * gate_w[k * 2 * IN_CH + i];
        lgt[tid] = tau[0] * (d + gate_b[k]);
    }
    __syncthreads();
    if (tid == 0) {
        float pr[16];
        float i0 = 0.f, i1 = 0.f, sp = 0.f;
        for (int b = 0; b < NB; ++b) {
            float a = lgt[b * 2], c2 = lgt[b * 2 + 1];
            float mx = fmaxf(a, c2);
            float e0 = expf(a - mx), e1 = expf(c2 - mx);
            float inv = 1.f / (e0 + e1);
            float q0 = e0 * inv, q1 = e1 * inv;
            pr[b * 2] = q0; pr[b * 2 + 1] = q1;
            i0 += q0; i1 += q1;
            float nrm = sqrtf(q0 * q0 + q1 * q1) + 1e-8f;
            sp += (q0 + q1) / nrm;
        }
        losses[0] = 0.1f * sp * (1.f / 8.f);
        i0 *= (1.f / 8.f); i1 *= (1.f / 8.f);
        float meanI = 0.5f * (i0 + i1);
        float stdI  = fabsf(i0 - i1) * 0.7071067811865476f;
        float cv = stdI / (meanI + 1e-8f);
        losses[1] = 0.01f * cv * cv;
        for (int t = 0; t < 16; ++t) probs[t] = pr[t];
    }
}

// ---------- 4. fused GEMM1(relu)+GEMM2 -> mixed output (unchanged from R10) ----
__global__ __launch_bounds__(256, 2) void gemm_kernel(
    const float* __restrict__ x,
    const unsigned short* __restrict__ w1b,   // [2048][256] bf16
    const unsigned short* __restrict__ w2b,   // [256][2048] bf16
    const float* __restrict__ b1,
    const float* __restrict__ probs,          // [8][2]
    unsigned short* __restrict__ mix) {       // [32000][256] bf16 (pre-mixed)
    __shared__ __align__(16) unsigned short w1c[64 * 256];   // 32 KB
    __shared__ __align__(16) unsigned short w2c[256 * 64];   // 32 KB
    __shared__ __align__(16) unsigned short f1t[64 * F1LD];  // 8.25 KB

    const int tid   = threadIdx.x;
    const int lane  = tid & 63;
    const int wv    = tid >> 6;       // 0..3
    const int rb    = wv & 1;         // 32-row band
    const int ch    = wv >> 1;        // 0..1 oc half (128 each)
    const int m0    = blockIdx.x * 64;
    const int l15   = lane & 15;
    const int lg    = lane >> 4;      // 0..3

    bf16x8 xr[2][8];
#pragma unroll
    for (int rt = 0; rt < 2; ++rt) {
        const float* xrow = x + (size_t)(m0 + rb * 32 + rt * 16 + l15) * IN_CH;
#pragma unroll
        for (int kk = 0; kk < 8; ++kk) {
            float4 v0 = *reinterpret_cast<const float4*>(xrow + kk * 32 + lg * 8);
            float4 v1 = *reinterpret_cast<const float4*>(xrow + kk * 32 + lg * 8 + 4);
            bf16x8 h;
            h[0] = (__bf16)v0.x; h[1] = (__bf16)v0.y; h[2] = (__bf16)v0.z; h[3] = (__bf16)v0.w;
            h[4] = (__bf16)v1.x; h[5] = (__bf16)v1.y; h[6] = (__bf16)v1.z; h[7] = (__bf16)v1.w;
            xr[rt][kk] = h;
        }
    }

    f32x4 acc2[2][8];
#pragma unroll
    for (int rt = 0; rt < 2; ++rt)
#pragma unroll
        for (int t = 0; t < 8; ++t) { acc2[rt][t][0]=0.f; acc2[rt][t][1]=0.f; acc2[rt][t][2]=0.f; acc2[rt][t][3]=0.f; }

#pragma unroll 1
    for (int chunk = 0; chunk < 32; ++chunk) {
        {
            const int h0 = chunk * 64;
            const unsigned short* w1s = w1b + (size_t)h0 * IN_CH;
            const unsigned short* w2s = w2b + h0;
#pragma unroll
            for (int i = 0; i < 8; ++i) {
                int seg = i * 4 + wv;                       // 0..31
                int r1 = seg * 2 + (lane >> 5);
                int c1 = ((lane & 31) * 8) ^ ((r1 & 7) << 3);
                GLOAD_LDS16(w1s + r1 * 256 + c1, &w1c[seg * 512]);
                int r2 = seg * 8 + (lane >> 3);
                int c2 = ((lane & 7) * 8) ^ ((r2 & 7) << 3);
                GLOAD_LDS16(w2s + (size_t)r2 * HIDDEN + c2, &w2c[seg * 512]);
            }
        }

        __syncthreads();   // [A] vmcnt drained -> weights ready

        f32x4 acc1[2][2];
#pragma unroll
        for (int rt = 0; rt < 2; ++rt)
#pragma unroll
            for (int ht = 0; ht < 2; ++ht) { acc1[rt][ht][0]=0.f; acc1[rt][ht][1]=0.f; acc1[rt][ht][2]=0.f; acc1[rt][ht][3]=0.f; }
#pragma unroll
        for (int kk = 0; kk < 8; ++kk) {
            const int kE = kk * 32 + lg * 8;
            bf16x8 bb[2];
#pragma unroll
            for (int ht = 0; ht < 2; ++ht) {
                const int hl = ch * 32 + ht * 16 + l15;
                bb[ht] = *reinterpret_cast<const bf16x8*>(
                    &w1c[hl * 256 + (kE ^ ((hl & 7) << 3))]);
            }
#pragma unroll
            for (int rt = 0; rt < 2; ++rt)
#pragma unroll
                for (int ht = 0; ht < 2; ++ht)
                    acc1[rt][ht] = __builtin_amdgcn_mfma_f32_16x16x32_bf16(
                        xr[rt][kk], bb[ht], acc1[rt][ht], 0, 0, 0);
        }
#pragma unroll
        for (int ht = 0; ht < 2; ++ht) {
            const int hl = ch * 32 + ht * 16 + l15;
            const float bias = b1[chunk * 64 + hl];   // L2-hit scalar
#pragma unroll
            for (int rt = 0; rt < 2; ++rt)
#pragma unroll
                for (int r = 0; r < 4; ++r) {
                    float v = fmaxf(acc1[rt][ht][r] + bias, 0.f);
                    int rr = rb * 32 + rt * 16 + lg * 4 + r;
                    f1t[rr * F1LD + hl] = bfbits(v);
                }
        }

        __syncthreads();   // [B] f1t ready

#pragma unroll
        for (int kk = 0; kk < 2; ++kk) {
            const int kE = kk * 32 + lg * 8;
            bf16x8 a2[2];
#pragma unroll
            for (int rt = 0; rt < 2; ++rt)
                a2[rt] = *reinterpret_cast<const bf16x8*>(
                    &f1t[(rb * 32 + rt * 16 + l15) * F1LD + kE]);
#pragma unroll
            for (int t = 0; t < 8; ++t) {
                int oc = ch * 128 + t * 16 + l15;
                bf16x8 b2 = *reinterpret_cast<const bf16x8*>(
                    &w2c[oc * 64 + (kE ^ ((oc & 7) << 3))]);
#pragma unroll
                for (int rt = 0; rt < 2; ++rt)
                    acc2[rt][t] = __builtin_amdgcn_mfma_f32_16x16x32_bf16(
                        a2[rt], b2, acc2[rt][t], 0, 0, 0);
            }
        }

        if (chunk == 3) {   // small branch done: rescale so p0*acc2 = p0*full+p1*small
#pragma unroll
            for (int rt = 0; rt < 2; ++rt)
#pragma unroll
                for (int r = 0; r < 4; ++r) {
                    int rr = m0 + rb * 32 + rt * 16 + lg * 4 + r;
                    int bb = rr / 4000;
                    float p0 = probs[bb * 2], p1 = probs[bb * 2 + 1];
                    float ratio = (p0 + p1) / fmaxf(p0, 1e-30f);
#pragma unroll
                    for (int t = 0; t < 8; ++t)
                        acc2[rt][t][r] *= ratio;
                }
        }

        __syncthreads();   // [C] reads done -> next stage may overwrite
    }
    // final: mix = p0 * acc2 (= p0*full + p1*small)
#pragma unroll
    for (int rt = 0; rt < 2; ++rt)
#pragma unroll
        for (int r = 0; r < 4; ++r) {
            int rr = m0 + rb * 32 + rt * 16 + lg * 4 + r;
            int bb = rr / 4000;
            float p0 = probs[bb * 2];
#pragma unroll
            for (int t = 0; t < 8; ++t) {
                int oc = ch * 128 + t * 16 + l15;
                mix[(size_t)rr * OUT_CH + oc] = bfbits(p0 * acc2[rt][t][r]);
            }
        }
}

// ---------- 5. depthwise conv (39 taps) + identity, LDS-staged single array ----
// 256 blocks (8 b x 32 tiles of 128 t) x 512 threads. LDS [166][256] bf16 = 85KB.
// Stage: pure u16x8 copy (mix is pre-blended by gemm). Compute: thread =
// (channel c, t-half th); 4 groups of 16 outputs, 54-row window -> 216 u16
// LDS reads/thread (R9's 8-out groups: 368). u16 column reads are 2-way
// bank-aliased (free). All register indices static: vwin[54]+acc[16]+cw[39].
#define CTT 128                 // t outputs per block
#define CROWS (CTT + 38)        // 166 staged rows
__global__ __launch_bounds__(512, 1) void conv_kernel(
    const unsigned short* __restrict__ mix,
    const float* __restrict__ conv_w,   // [256][1][39]
    float* __restrict__ out) {
    __shared__ __align__(16) unsigned short lds[CROWS * 256];

    const int tid = threadIdx.x;
    const int blk = blockIdx.x;
    const int b   = blk >> 5;
    const int t0  = (blk & 31) * CTT;

    // ---- stage: 166*256/8 = 5312 u16x8 chunks ----
#pragma unroll
    for (int it = 0; it < 11; ++it) {
        int chunk = it * 512 + tid;
        if (it == 10 && tid >= 192) break;
        int e = chunk * 8;
        int s = e >> 8, c = e & 255;
        int t = t0 - 19 + s;
        u16x8 o;
        if (t >= 0 && t < NT) {
            o = *reinterpret_cast<const u16x8*>(&mix[((size_t)b * NT + t) * OUT_CH + c]);
        } else {
#pragma unroll
            for (int k = 0; k < 8; ++k) o[k] = 0;
        }
        *reinterpret_cast<u16x8*>(&lds[s * 256 + c]) = o;
    }
    __syncthreads();

    const int c  = tid & 255;
    const int th = tid >> 8;          // 0 or 1
    float cw[39];
#pragma unroll
    for (int j = 0; j < 39; ++j) cw[j] = conv_w[c * 39 + j];

#pragma unroll 1
    for (int g = 0; g < 4; ++g) {
        const int u0 = th * 64 + g * 16;   // row offset in tile
        float vwin[54];
#pragma unroll
        for (int i = 0; i < 54; ++i)
            vwin[i] = bf2f(lds[(u0 + i) * 256 + c]);
        float acc[16];
#pragma unroll
        for (int o = 0; o < 16; ++o) {
            float a = vwin[o + 19];          // identity (xp + conv)
#pragma unroll
            for (int j = 0; j < 39; ++j)
                a += cw[j] * vwin[o + j];
            acc[o] = a;
        }
        const int tbase = t0 + u0;
#pragma unroll
        for (int o = 0; o < 16; ++o) {
            int t = tbase + o;
            if (t < NT)
                out[((size_t)b * NT + t) * OUT_CH + c] = acc[o];
        }
    }
}

// ---------- launch ----------
extern "C" void kernel_launch(void* const* d_in, const int* in_sizes, int n_in,
                              void* d_out, int out_size, void* d_ws, size_t ws_size,
                              hipStream_t stream) {
    const float* x      = (const float*)d_in[0];
    const float* w1     = (const float*)d_in[1];
    const float* b1     = (const float*)d_in[2];
    const float* w2     = (const float*)d_in[3];
    const float* conv_w = (const float*)d_in[4];
    const float* gate_w = (const float*)d_in[5];
    const float* gate_b = (const float*)d_in[6];
    const float* tau    = (const float*)d_in[7];
    float* out = (float*)d_out;

    char* ws = (char*)d_ws;
    unsigned short* w1b = (unsigned short*)(ws);
    unsigned short* w2b = (unsigned short*)(ws + 1048576);
    unsigned short* mix = (unsigned short*)(ws + 2097152);
    float* psum  = (float*)(ws + 2097152 + 2 * 16384000);
    float* psq   = psum + 256 * 256;
    float* probs = psq + 256 * 256;

    cvt_kernel<<<dim3(512), dim3(256), 0, stream>>>(w1, w1b, 131072);
    cvt_kernel<<<dim3(512), dim3(256), 0, stream>>>(w2, w2b, 131072);
    reduce_kernel<<<dim3(256), dim3(256), 0, stream>>>(x, psum, psq);
    gate_kernel<<<dim3(1), dim3(256), 0, stream>>>(psum, psq, gate_w, gate_b, tau,
                                                   probs, out + 8192000);
    gemm_kernel<<<dim3(500), dim3(256), 0, stream>>>(x, w1b, w2b, b1, probs, mix);
    conv_kernel<<<dim3(256), dim3(512), 0, stream>>>(mix, conv_w, out);
}

// Round 12
// 165.173 us; speedup vs baseline: 1.2577x; 1.0149x over previous
//
#include <hip/hip_runtime.h>

// ---------- types ----------
typedef __bf16 bf16x8 __attribute__((ext_vector_type(8)));
typedef float  f32x4  __attribute__((ext_vector_type(4)));
typedef unsigned short u16x8 __attribute__((ext_vector_type(8)));

#define IN_CH  256
#define OUT_CH 256
#define HIDDEN 2048
#define NB     8
#define NT     4000
#define NROW   32000   // NB*NT
#define F1LD   66      // f1t leading dim (odd word stride -> spread banks)

__device__ __forceinline__ unsigned short bfbits(float f) {
    __bf16 h = (__bf16)f;                       // native cvt (RTNE)
    return *reinterpret_cast<unsigned short*>(&h);
}
__device__ __forceinline__ float bf2f(unsigned short h) {
    return __uint_as_float(((unsigned)h) << 16);
}

#define GLOAD_LDS16(g, l) \
    __builtin_amdgcn_global_load_lds((const __attribute__((address_space(1))) void*)(g), \
                                     (__attribute__((address_space(3))) void*)(l), 16, 0, 0)

// ---------- 1. fp32 -> bf16 convert (both weight tensors, one launch) ----------
__global__ void cvt_kernel(const float* __restrict__ w1,
                           unsigned short* __restrict__ w1o,
                           const float* __restrict__ w2,
                           unsigned short* __restrict__ w2o) {
    int i = blockIdx.x * blockDim.x + threadIdx.x;   // 0..262143
    const float* in;
    unsigned short* outp;
    int j;
    if (i < 131072) { in = w1; outp = w1o; j = i; }
    else            { in = w2; outp = w2o; j = i - 131072; }
    float4 v = reinterpret_cast<const float4*>(in)[j];
    ushort4 o;
    o.x = bfbits(v.x); o.y = bfbits(v.y); o.z = bfbits(v.z); o.w = bfbits(v.w);
    reinterpret_cast<ushort4*>(outp)[j] = o;
}

// ---------- 2. partial mean/var reduction over T ----------
__global__ void reduce_kernel(const float* __restrict__ x,
                              float* __restrict__ psum, float* __restrict__ psq) {
    int c = threadIdx.x;
    int blk = blockIdx.x;
    int b = blk >> 5, tc = blk & 31;
    const float* base = x + ((size_t)b * NT + tc * 125) * IN_CH + c;
    float s = 0.f, q = 0.f;
    for (int t = 0; t < 125; ++t) {
        float v = base[(size_t)t * IN_CH];
        s += v; q += v * v;
    }
    psum[blk * IN_CH + c] = s;
    psq [blk * IN_CH + c] = q;
}

// ---------- 3. gate: mean/std -> logits -> probs -> losses ----------
__global__ __launch_bounds__(256) void gate_kernel(
    const float* __restrict__ psum, const float* __restrict__ psq,
    const float* __restrict__ gate_w, const float* __restrict__ gate_b,
    const float* __restrict__ tau, float* __restrict__ probs,
    float* __restrict__ losses) {
    __shared__ float gi[NB][2 * IN_CH];
    __shared__ float lgt[16];
    int tid = threadIdx.x;
    for (int b = 0; b < NB; ++b) {
        float s = 0.f, q = 0.f;
        for (int p = 0; p < 32; ++p) {
            s += psum[(b * 32 + p) * IN_CH + tid];
            q += psq [(b * 32 + p) * IN_CH + tid];
        }
        float mean = s * (1.f / 4000.f);
        float var  = (q - s * s * (1.f / 4000.f)) * (1.f / 3999.f);  // ddof=1
        gi[b][tid]          = mean;
        gi[b][IN_CH + tid]  = sqrtf(fmaxf(var, 0.f));
    }
    __syncthreads();
    if (tid < 16) {
        int b = tid >> 1, k = tid & 1;
        float d = 0.f;
        for (int i = 0; i < 2 * IN_CH; ++i) d += gi[b][i] * gate_w[k * 2 * IN_CH + i];
        lgt[tid] = tau[0] * (d + gate_b[k]);
    }
    __syncthreads();
    if (tid == 0) {
        float pr[16];
        float i0 = 0.f, i1 = 0.f, sp = 0.f;
        for (int b = 0; b < NB; ++b) {
            float a = lgt[b * 2], c2 = lgt[b * 2 + 1];
            float mx = fmaxf(a, c2);
            float e0 = expf(a - mx), e1 = expf(c2 - mx);
            float inv = 1.f / (e0 + e1);
            float q0 = e0 * inv, q1 = e1 * inv;
            pr[b * 2] = q0; pr[b * 2 + 1] = q1;
            i0 += q0; i1 += q1;
            float nrm = sqrtf(q0 * q0 + q1 * q1) + 1e-8f;
            sp += (q0 + q1) / nrm;
        }
        losses[0] = 0.1f * sp * (1.f / 8.f);
        i0 *= (1.f / 8.f); i1 *= (1.f / 8.f);
        float meanI = 0.5f * (i0 + i1);
        float stdI  = fabsf(i0 - i1) * 0.7071067811865476f;
        float cv = stdI / (meanI + 1e-8f);
        losses[1] = 0.01f * cv * cv;
        for (int t = 0; t < 16; ++t) probs[t] = pr[t];
    }
}

// ---------- 4. fused GEMM1(relu)+GEMM2 -> mixed output (unchanged from R10) ----
__global__ __launch_bounds__(256, 2) void gemm_kernel(
    const float* __restrict__ x,
    const unsigned short* __restrict__ w1b,   // [2048][256] bf16
    const unsigned short* __restrict__ w2b,   // [256][2048] bf16
    const float* __restrict__ b1,
    const float* __restrict__ probs,          // [8][2]
    unsigned short* __restrict__ mix) {       // [32000][256] bf16 (pre-mixed)
    __shared__ __align__(16) unsigned short w1c[64 * 256];   // 32 KB
    __shared__ __align__(16) unsigned short w2c[256 * 64];   // 32 KB
    __shared__ __align__(16) unsigned short f1t[64 * F1LD];  // 8.25 KB

    const int tid   = threadIdx.x;
    const int lane  = tid & 63;
    const int wv    = tid >> 6;       // 0..3
    const int rb    = wv & 1;         // 32-row band
    const int ch    = wv >> 1;        // 0..1 oc half (128 each)
    const int m0    = blockIdx.x * 64;
    const int l15   = lane & 15;
    const int lg    = lane >> 4;      // 0..3

    bf16x8 xr[2][8];
#pragma unroll
    for (int rt = 0; rt < 2; ++rt) {
        const float* xrow = x + (size_t)(m0 + rb * 32 + rt * 16 + l15) * IN_CH;
#pragma unroll
        for (int kk = 0; kk < 8; ++kk) {
            float4 v0 = *reinterpret_cast<const float4*>(xrow + kk * 32 + lg * 8);
            float4 v1 = *reinterpret_cast<const float4*>(xrow + kk * 32 + lg * 8 + 4);
            bf16x8 h;
            h[0] = (__bf16)v0.x; h[1] = (__bf16)v0.y; h[2] = (__bf16)v0.z; h[3] = (__bf16)v0.w;
            h[4] = (__bf16)v1.x; h[5] = (__bf16)v1.y; h[6] = (__bf16)v1.z; h[7] = (__bf16)v1.w;
            xr[rt][kk] = h;
        }
    }

    f32x4 acc2[2][8];
#pragma unroll
    for (int rt = 0; rt < 2; ++rt)
#pragma unroll
        for (int t = 0; t < 8; ++t) { acc2[rt][t][0]=0.f; acc2[rt][t][1]=0.f; acc2[rt][t][2]=0.f; acc2[rt][t][3]=0.f; }

#pragma unroll 1
    for (int chunk = 0; chunk < 32; ++chunk) {
        {
            const int h0 = chunk * 64;
            const unsigned short* w1s = w1b + (size_t)h0 * IN_CH;
            const unsigned short* w2s = w2b + h0;
#pragma unroll
            for (int i = 0; i < 8; ++i) {
                int seg = i * 4 + wv;                       // 0..31
                int r1 = seg * 2 + (lane >> 5);
                int c1 = ((lane & 31) * 8) ^ ((r1 & 7) << 3);
                GLOAD_LDS16(w1s + r1 * 256 + c1, &w1c[seg * 512]);
                int r2 = seg * 8 + (lane >> 3);
                int c2 = ((lane & 7) * 8) ^ ((r2 & 7) << 3);
                GLOAD_LDS16(w2s + (size_t)r2 * HIDDEN + c2, &w2c[seg * 512]);
            }
        }

        __syncthreads();   // [A] vmcnt drained -> weights ready

        f32x4 acc1[2][2];
#pragma unroll
        for (int rt = 0; rt < 2; ++rt)
#pragma unroll
            for (int ht = 0; ht < 2; ++ht) { acc1[rt][ht][0]=0.f; acc1[rt][ht][1]=0.f; acc1[rt][ht][2]=0.f; acc1[rt][ht][3]=0.f; }
#pragma unroll
        for (int kk = 0; kk < 8; ++kk) {
            const int kE = kk * 32 + lg * 8;
            bf16x8 bb[2];
#pragma unroll
            for (int ht = 0; ht < 2; ++ht) {
                const int hl = ch * 32 + ht * 16 + l15;
                bb[ht] = *reinterpret_cast<const bf16x8*>(
                    &w1c[hl * 256 + (kE ^ ((hl & 7) << 3))]);
            }
#pragma unroll
            for (int rt = 0; rt < 2; ++rt)
#pragma unroll
                for (int ht = 0; ht < 2; ++ht)
                    acc1[rt][ht] = __builtin_amdgcn_mfma_f32_16x16x32_bf16(
                        xr[rt][kk], bb[ht], acc1[rt][ht], 0, 0, 0);
        }
#pragma unroll
        for (int ht = 0; ht < 2; ++ht) {
            const int hl = ch * 32 + ht * 16 + l15;
            const float bias = b1[chunk * 64 + hl];   // L2-hit scalar
#pragma unroll
            for (int rt = 0; rt < 2; ++rt)
#pragma unroll
                for (int r = 0; r < 4; ++r) {
                    float v = fmaxf(acc1[rt][ht][r] + bias, 0.f);
                    int rr = rb * 32 + rt * 16 + lg * 4 + r;
                    f1t[rr * F1LD + hl] = bfbits(v);
                }
        }

        __syncthreads();   // [B] f1t ready

#pragma unroll
        for (int kk = 0; kk < 2; ++kk) {
            const int kE = kk * 32 + lg * 8;
            bf16x8 a2[2];
#pragma unroll
            for (int rt = 0; rt < 2; ++rt)
                a2[rt] = *reinterpret_cast<const bf16x8*>(
                    &f1t[(rb * 32 + rt * 16 + l15) * F1LD + kE]);
#pragma unroll
            for (int t = 0; t < 8; ++t) {
                int oc = ch * 128 + t * 16 + l15;
                bf16x8 b2 = *reinterpret_cast<const bf16x8*>(
                    &w2c[oc * 64 + (kE ^ ((oc & 7) << 3))]);
#pragma unroll
                for (int rt = 0; rt < 2; ++rt)
                    acc2[rt][t] = __builtin_amdgcn_mfma_f32_16x16x32_bf16(
                        a2[rt], b2, acc2[rt][t], 0, 0, 0);
            }
        }

        if (chunk == 3) {   // small branch done: rescale so p0*acc2 = p0*full+p1*small
#pragma unroll
            for (int rt = 0; rt < 2; ++rt)
#pragma unroll
                for (int r = 0; r < 4; ++r) {
                    int rr = m0 + rb * 32 + rt * 16 + lg * 4 + r;
                    int bb = rr / 4000;
                    float p0 = probs[bb * 2], p1 = probs[bb * 2 + 1];
                    float ratio = (p0 + p1) / fmaxf(p0, 1e-30f);
#pragma unroll
                    for (int t = 0; t < 8; ++t)
                        acc2[rt][t][r] *= ratio;
                }
        }

        __syncthreads();   // [C] reads done -> next stage may overwrite
    }
    // final: mix = p0 * acc2 (= p0*full + p1*small)
#pragma unroll
    for (int rt = 0; rt < 2; ++rt)
#pragma unroll
        for (int r = 0; r < 4; ++r) {
            int rr = m0 + rb * 32 + rt * 16 + lg * 4 + r;
            int bb = rr / 4000;
            float p0 = probs[bb * 2];
#pragma unroll
            for (int t = 0; t < 8; ++t) {
                int oc = ch * 128 + t * 16 + l15;
                mix[(size_t)rr * OUT_CH + oc] = bfbits(p0 * acc2[rt][t][r]);
            }
        }
}

// ---------- 5. depthwise conv (39 taps) + identity, LDS-staged, 256 threads ----
// R11's conv used 512-thread blocks -> hard 128-VGPR cap (proven R4/R5) ->
// vwin[54]+acc[16]+cw[39] ~150 regs spilled to scratch. 256-thread blocks
// allow 256 VGPRs: no spill. Tile 64 t, LDS [102][256] bf16 = 51 KB ->
// 2 blocks/CU. 504 blocks (8 b x 63 tiles). Thread = channel c; 4 groups
// of 16 outputs, 54-row window, all register indices compile-time static.
#define CT2 64                  // t outputs per block
#define CR2 (CT2 + 38)          // 102 staged rows
__global__ __launch_bounds__(256, 2) void conv_kernel(
    const unsigned short* __restrict__ mix,
    const float* __restrict__ conv_w,   // [256][1][39]
    float* __restrict__ out) {
    __shared__ __align__(16) unsigned short lds[CR2 * 256];   // 51 KB

    const int tid = threadIdx.x;
    const int blk = blockIdx.x;
    const int b   = blk / 63;
    const int t0  = (blk % 63) * CT2;

    // ---- stage: 102*256/8 = 3264 u16x8 chunks, 256 threads ----
#pragma unroll
    for (int it = 0; it < 13; ++it) {
        int chunk = it * 256 + tid;
        if (it == 12 && tid >= 192) break;
        int e = chunk * 8;
        int s = e >> 8, c = e & 255;
        int t = t0 - 19 + s;
        u16x8 o;
        if (t >= 0 && t < NT) {
            o = *reinterpret_cast<const u16x8*>(&mix[((size_t)b * NT + t) * OUT_CH + c]);
        } else {
#pragma unroll
            for (int k = 0; k < 8; ++k) o[k] = 0;
        }
        *reinterpret_cast<u16x8*>(&lds[s * 256 + c]) = o;
    }
    __syncthreads();

    const int c = tid;
    float cw[39];
#pragma unroll
    for (int j = 0; j < 39; ++j) cw[j] = conv_w[c * 39 + j];

#pragma unroll 1
    for (int g = 0; g < 4; ++g) {
        const int u0 = g * 16;   // row offset in tile
        float vwin[54];
#pragma unroll
        for (int i = 0; i < 54; ++i)
            vwin[i] = bf2f(lds[(u0 + i) * 256 + c]);
        float acc[16];
#pragma unroll
        for (int o = 0; o < 16; ++o) {
            float a = vwin[o + 19];          // identity (xp + conv)
#pragma unroll
            for (int j = 0; j < 39; ++j)
                a += cw[j] * vwin[o + j];
            acc[o] = a;
        }
        const int tbase = t0 + u0;
#pragma unroll
        for (int o = 0; o < 16; ++o) {
            int t = tbase + o;
            if (t < NT)
                out[((size_t)b * NT + t) * OUT_CH + c] = acc[o];
        }
    }
}

// ---------- launch ----------
extern "C" void kernel_launch(void* const* d_in, const int* in_sizes, int n_in,
                              void* d_out, int out_size, void* d_ws, size_t ws_size,
                              hipStream_t stream) {
    const float* x      = (const float*)d_in[0];
    const float* w1     = (const float*)d_in[1];
    const float* b1     = (const float*)d_in[2];
    const float* w2     = (const float*)d_in[3];
    const float* conv_w = (const float*)d_in[4];
    const float* gate_w = (const float*)d_in[5];
    const float* gate_b = (const float*)d_in[6];
    const float* tau    = (const float*)d_in[7];
    float* out = (float*)d_out;

    char* ws = (char*)d_ws;
    unsigned short* w1b = (unsigned short*)(ws);
    unsigned short* w2b = (unsigned short*)(ws + 1048576);
    unsigned short* mix = (unsigned short*)(ws + 2097152);
    float* psum  = (float*)(ws + 2097152 + 2 * 16384000);
    float* psq   = psum + 256 * 256;
    float* probs = psq + 256 * 256;

    cvt_kernel<<<dim3(1024), dim3(256), 0, stream>>>(w1, w1b, w2, w2b);
    reduce_kernel<<<dim3(256), dim3(256), 0, stream>>>(x, psum, psq);
    gate_kernel<<<dim3(1), dim3(256), 0, stream>>>(psum, psq, gate_w, gate_b, tau,
                                                   probs, out + 8192000);
    gemm_kernel<<<dim3(500), dim3(256), 0, stream>>>(x, w1b, w2b, b1, probs, mix);
    conv_kernel<<<dim3(504), dim3(256), 0, stream>>>(mix, conv_w, out);
}